// Round 8
// baseline (184.114 us; speedup 1.0000x reference)
//
#include <hip/hip_runtime.h>
#include <hip/hip_bf16.h>

// Feature-slice GNN with in-register aggregation operands (R6 structure) +
// persistent-ish blocks: each block processes 2 graph-pairs (4 graphs),
// grid = nB/4 = 512 = exactly one residency round (2 blocks/CU).
//  - sS staging + w1 fragments amortized over 2 pairs (1 extra barrier total)
//  - pair-2 x loads issued before barrier B of pair-1 (HBM hides under S5)
//  - S3's 8 w2 b128 loads hoisted above barrier A (L2 latency hides in wait)
// 512 threads = 8 waves; waves 0-3 = graph A, waves 4-7 = graph B of the
// current pair; each wave owns a 32-feature slice for all 96 (padded) cells.
// D-tile of t = x@W1 packed to bf16 pairs IS the B-operand of h = S@t
// (S A-frags repacked: k-slot q*8+j <-> cell (2s+(j>>2))*16+q*4+(j&3));
// S1->S2 and S3->S4 are register-only handoffs. Only h crosses waves.
// Cross-pair hazards: pair2 hS writes only after pair2-barrier-A-arrival of
// all waves (which is after all pair1 S3 hS reads / S5 sPool reads) -- safe.
// launch_bounds(512,4) -> 128-reg cap guarantees 2 blocks/CU (512-reg file).
typedef __attribute__((ext_vector_type(8))) short bf16x8;
typedef __attribute__((ext_vector_type(4))) float f32x4;

__device__ __forceinline__ unsigned short f2b(float f) {
    __hip_bfloat16 h = __float2bfloat16(f);
    return __builtin_bit_cast(unsigned short, h);
}
__device__ __forceinline__ float b2f(unsigned short u) {
    unsigned v = ((unsigned)u) << 16;
    return __builtin_bit_cast(float, v);
}
__device__ __forceinline__ float ldf(const void* p, int idx, bool f32) {
    return f32 ? ((const float*)p)[idx] : b2f(((const unsigned short*)p)[idx]);
}
__device__ __forceinline__ unsigned short ldb(const void* p, int idx, bool f32) {
    return f32 ? f2b(((const float*)p)[idx]) : ((const unsigned short*)p)[idx];
}
// XOR chunk swizzle: 128-ushort rows, 8-ushort chunks -> bank-uniform
__device__ __forceinline__ int swz(int row, int col) {
    return row * 128 + (((col >> 3) ^ (row & 7)) << 3) + (col & 7);
}
__device__ __forceinline__ uint2 pk4(f32x4 c) {
    unsigned lo = (unsigned)f2b(c[0]) | ((unsigned)f2b(c[1]) << 16);
    unsigned hi = (unsigned)f2b(c[2]) | ((unsigned)f2b(c[3]) << 16);
    return make_uint2(lo, hi);
}
__device__ __forceinline__ bf16x8 mkB(uint2 a, uint2 b) {
    return __builtin_bit_cast(bf16x8, make_uint4(a.x, a.y, b.x, b.y));
}

// dtype sniff from a uniform 64B of x (fp32 mantissa ushorts -> wild exponents)
__device__ __forceinline__ bool sniff_f32(const void* x) {
    const unsigned* p = (const unsigned*)x;
    int wild = 0;
#pragma unroll
    for (int i = 0; i < 16; ++i) {
        unsigned e = (p[i] >> 7) & 0xFF;
        wild += (e != 0 && (e < 0x68 || e > 0x90)) ? 1 : 0;
    }
    return wild > 8;
}

// ---- ws layout (bytes) ----
#define WS_B1F    16        // 128 f32
#define WS_B2F    528       // 128 f32
#define WS_BHF    1040      // 104 f32
#define WS_W1R    1536      // 128*32 bf16   [f][k]
#define WS_W2R    9728      // 128*128 bf16  [f][k]
#define WS_SR     42496     // 18*64*8 bf16  A-frags [(mt*3+s)*64+lane][j]
#define WS_WH     60928     // 104*128 f32   [o][f]

__global__ void k_repack(const void* __restrict__ x,
                         const void* __restrict__ W1, const void* __restrict__ b1,
                         const void* __restrict__ W2, const void* __restrict__ b2,
                         const void* __restrict__ Wa, const void* __restrict__ ba,
                         const void* __restrict__ Wc, const void* __restrict__ bc,
                         const void* __restrict__ Wn, const void* __restrict__ bn,
                         const void* __restrict__ Wt, const void* __restrict__ bt,
                         char* __restrict__ ws) {
    const bool f32 = sniff_f32(x);
    int idx = blockIdx.x * blockDim.x + threadIdx.x;
    if (idx < 4096) {                         // w1r [f][k]
        int f = idx >> 5, k = idx & 31;
        unsigned short v = (k < 10) ? ldb(W1, k * 128 + f, f32) : (unsigned short)0;
        ((unsigned short*)(ws + WS_W1R))[idx] = v;
        return;
    }
    idx -= 4096;
    if (idx < 16384) {                        // w2r [f][k]
        int f = idx >> 7, k = idx & 127;
        ((unsigned short*)(ws + WS_W2R))[idx] = ldb(W2, k * 128 + f, f32);
        return;
    }
    idx -= 16384;
    if (idx < 9216) {                         // S A-frags, reg-handoff slot layout
        int fi = idx >> 9, rem = idx & 511;
        int lane = rem >> 3, j = rem & 7;
        int mt = fi / 3, s = fi - mt * 3;
        int node = mt * 16 + (lane & 15);                       // m row
        int qa = lane >> 4;                                     // 0..3
        int cell = (2 * s + (j >> 2)) * 16 + qa * 4 + (j & 3);  // k slot -> cell
        bool adj = false;
        if (node < 81 && cell < 81) {
            int ni = node / 9, nj = node % 9;
            int ci = cell / 9, cj = cell % 9;
            adj = (ni == ci) || (nj == cj) ||
                  ((ni / 3 == ci / 3) && (nj / 3 == cj / 3));
        }
        ((unsigned short*)(ws + WS_SR))[idx] = adj ? (unsigned short)0x3F80 : (unsigned short)0;
        return;
    }
    idx -= 9216;
    if (idx < 13312) {                        // head weights (f32) [o][f]
        int o = idx >> 7, f = idx & 127;
        const void* W; int oo, dim;
        if (o < 4)       { W = Wa; oo = o;      dim = 4;  }
        else if (o < 85) { W = Wc; oo = o - 4;  dim = 81; }
        else if (o < 94) { W = Wn; oo = o - 85; dim = 9;  }
        else             { W = Wt; oo = o - 94; dim = 10; }
        ((float*)(ws + WS_WH))[idx] = ldf(W, f * dim + oo, f32);
        return;
    }
    idx -= 13312;
    if (idx < 360) {                          // biases
        float v;
        if (idx < 128)      v = ldf(b1, idx, f32);
        else if (idx < 256) v = ldf(b2, idx - 128, f32);
        else {
            int o = idx - 256;
            if (o < 4)       v = ldf(ba, o, f32);
            else if (o < 85) v = ldf(bc, o - 4, f32);
            else if (o < 94) v = ldf(bn, o - 85, f32);
            else             v = ldf(bt, o - 94, f32);
        }
        if (idx < 128)      ((float*)(ws + WS_B1F))[idx] = v;
        else if (idx < 256) ((float*)(ws + WS_B2F))[idx - 128] = v;
        else                ((float*)(ws + WS_BHF))[idx - 256] = v;
    }
}

__global__ __launch_bounds__(512, 4) void sudoku_gnn(
    const void* __restrict__ x, const char* __restrict__ ws,
    void* __restrict__ out, int nB)
{
    __shared__ __attribute__((aligned(16))) unsigned short hS[2][12288]; // [96c][128f] swizzled
    __shared__ __attribute__((aligned(16))) unsigned short sS[9216];     // S A-frags
    __shared__ float sPool[2][128];

    const bool f32 = sniff_f32(x);
    const unsigned short* w1r = (const unsigned short*)(ws + WS_W1R);
    const unsigned short* w2r = (const unsigned short*)(ws + WS_W2R);
    const float* b1f = (const float*)(ws + WS_B1F);
    const float* b2f = (const float*)(ws + WS_B2F);
    const float* bhf = (const float*)(ws + WS_BHF);
    const float* whf = (const float*)(ws + WS_WH);

    const int tid  = threadIdx.x;
    const int wave = tid >> 6;
    const int gq   = wave >> 2;           // which graph of the pair
    const int lane = tid & 63;
    const int ln15 = lane & 15;
    const int q    = lane >> 4;
    const int k0   = q * 8;
    const int FB   = (wave & 3) * 32;     // wave's feature-slice base
    const int g0   = blockIdx.x * 4;      // 4 graphs per block (2 pairs)
    const float inv21 = 1.0f / 21.0f;
    const float inv81 = 1.0f / 81.0f;

    // ---- x raw prefetch (bf16 path) ----
    uint4 xr4[6]; unsigned xr1[6];
    auto rawload = [&](int gg_) {
        int gcl = (gg_ < nB) ? gg_ : nB - 1;
        const char* xg = (const char*)x + (size_t)gcl * 1620;
#pragma unroll
        for (int mt = 0; mt < 6; ++mt) {
            int node = mt * 16 + ln15;
            uint4 r = {0, 0, 0, 0}; unsigned r1v = 0;
            if (node < 81) {
                if (q == 0)      r   = *(const uint4*)(xg + node * 20);
                else if (q == 1) r1v = *(const unsigned*)(xg + node * 20 + 16);
            }
            xr4[mt] = r; xr1[mt] = r1v;
        }
    };
    if (!f32) rawload(g0 + gq);

    // ---- stage S A-frags into LDS (consumed after barrier 0) ----
    {
        const uint4* src = (const uint4*)(ws + WS_SR);
        uint4* dst = (uint4*)sS;
        for (int i = tid; i < 1152; i += 512) dst[i] = src[i];
    }

    // ---- W1 fragments (persistent across pairs) ----
    bf16x8 w1f[2];
#pragma unroll
    for (int fmt = 0; fmt < 2; ++fmt)
        w1f[fmt] = *(const bf16x8*)&w1r[(FB + fmt * 16 + ln15) * 32 + k0];

    const f32x4 z4 = {0.f, 0.f, 0.f, 0.f};

    __syncthreads();   // (0) sS staged

    for (int p = 0; p < 2; ++p) {
        const int g = (g0 + p * 2 + gq < nB) ? g0 + p * 2 + gq : nB - 1;

        // ---------- S1: t = x @ W1 ; D-tiles -> packed B-frag halves ----------
        uint2 tpk[6][2];
#pragma unroll
        for (int mt = 0; mt < 6; ++mt) {
            bf16x8 xv = {0, 0, 0, 0, 0, 0, 0, 0};
            if (!f32) {
                if (q == 0)      xv = __builtin_bit_cast(bf16x8, xr4[mt]);
                else if (q == 1) { xv[0] = (short)(xr1[mt] & 0xFFFF); xv[1] = (short)(xr1[mt] >> 16); }
            } else {
                int node = mt * 16 + ln15;
                if (node < 81) {
                    const float* xg = (const float*)x + (size_t)g * 810 + node * 10;
                    if (q == 0) {
#pragma unroll
                        for (int j = 0; j < 8; ++j) xv[j] = (short)f2b(xg[j]);
                    } else if (q == 1) {
                        xv[0] = (short)f2b(xg[8]);
                        xv[1] = (short)f2b(xg[9]);
                    }
                }
            }
#pragma unroll
            for (int fmt = 0; fmt < 2; ++fmt)
                tpk[mt][fmt] = pk4(__builtin_amdgcn_mfma_f32_16x16x32_bf16(xv, w1f[fmt], z4, 0, 0, 0));
        }

        f32x4 acc[6][2];

        // ---------- S2: h = S @ t (B from registers) ; relu(+b1) ----------
#pragma unroll
        for (int a = 0; a < 6; ++a)
#pragma unroll
            for (int c = 0; c < 2; ++c) acc[a][c] = z4;
#pragma unroll
        for (int s = 0; s < 3; ++s) {
            bf16x8 B[2];
#pragma unroll
            for (int fmt = 0; fmt < 2; ++fmt)
                B[fmt] = mkB(tpk[2 * s][fmt], tpk[2 * s + 1][fmt]);
#pragma unroll
            for (int mt = 0; mt < 6; ++mt) {
                bf16x8 afr = *(const bf16x8*)&sS[((mt * 3 + s) * 64 + lane) * 8];
#pragma unroll
                for (int fmt = 0; fmt < 2; ++fmt)
                    acc[mt][fmt] = __builtin_amdgcn_mfma_f32_16x16x32_bf16(afr, B[fmt], acc[mt][fmt], 0, 0, 0);
            }
        }
#pragma unroll
        for (int fmt = 0; fmt < 2; ++fmt) {
            float bias = b1f[FB + fmt * 16 + ln15];
#pragma unroll
            for (int mt = 0; mt < 6; ++mt)
#pragma unroll
                for (int r = 0; r < 4; ++r) {
                    int cell = mt * 16 + q * 4 + r;
                    float v = fmaxf(acc[mt][fmt][r] * inv21 + bias, 0.0f);
                    hS[gq][swz(cell, FB + fmt * 16 + ln15)] = f2b(v);
                }
        }

        // ---- hoist S3's w2 fragment loads above barrier A (L2 latency hides) ----
        bf16x8 w2f[4][2];
#pragma unroll
        for (int kc = 0; kc < 4; ++kc)
#pragma unroll
            for (int fmt = 0; fmt < 2; ++fmt)
                w2f[kc][fmt] = *(const bf16x8*)&w2r[(FB + fmt * 16 + ln15) * 128 + kc * 32 + k0];

        __syncthreads();   // (A) h complete before cross-wave S3 reads

        // ---------- S3: t2 = h @ W2 ; D-tiles -> packed B-frag halves ----------
#pragma unroll
        for (int a = 0; a < 6; ++a)
#pragma unroll
            for (int c = 0; c < 2; ++c) acc[a][c] = z4;
#pragma unroll
        for (int kc = 0; kc < 4; ++kc) {
#pragma unroll
            for (int mt = 0; mt < 6; ++mt) {
                bf16x8 a3 = *(const bf16x8*)&hS[gq][swz(mt * 16 + ln15, kc * 32 + k0)];
#pragma unroll
                for (int fmt = 0; fmt < 2; ++fmt)
                    acc[mt][fmt] = __builtin_amdgcn_mfma_f32_16x16x32_bf16(a3, w2f[kc][fmt], acc[mt][fmt], 0, 0, 0);
            }
        }
#pragma unroll
        for (int mt = 0; mt < 6; ++mt)
#pragma unroll
            for (int fmt = 0; fmt < 2; ++fmt)
                tpk[mt][fmt] = pk4(acc[mt][fmt]);

        // ---------- S4: h2 = S @ t2 (registers) ; relu(+b2) fused mean-pool ----------
#pragma unroll
        for (int a = 0; a < 6; ++a)
#pragma unroll
            for (int c = 0; c < 2; ++c) acc[a][c] = z4;
#pragma unroll
        for (int s = 0; s < 3; ++s) {
            bf16x8 B[2];
#pragma unroll
            for (int fmt = 0; fmt < 2; ++fmt)
                B[fmt] = mkB(tpk[2 * s][fmt], tpk[2 * s + 1][fmt]);
#pragma unroll
            for (int mt = 0; mt < 6; ++mt) {
                bf16x8 afr = *(const bf16x8*)&sS[((mt * 3 + s) * 64 + lane) * 8];
#pragma unroll
                for (int fmt = 0; fmt < 2; ++fmt)
                    acc[mt][fmt] = __builtin_amdgcn_mfma_f32_16x16x32_bf16(afr, B[fmt], acc[mt][fmt], 0, 0, 0);
            }
        }
#pragma unroll
        for (int fmt = 0; fmt < 2; ++fmt) {
            float bias = b2f[FB + fmt * 16 + ln15];
            float sum = 0.f;
#pragma unroll
            for (int mt = 0; mt < 6; ++mt)
#pragma unroll
                for (int r = 0; r < 4; ++r) {
                    int cell = mt * 16 + q * 4 + r;
                    float v = fmaxf(acc[mt][fmt][r] * inv21 + bias, 0.0f);
                    sum += (cell < 81) ? v : 0.0f;
                }
            sum += __shfl_xor(sum, 16);
            sum += __shfl_xor(sum, 32);
            if (lane < 16) sPool[gq][FB + fmt * 16 + lane] = sum * inv81;
        }

        // ---- prefetch next pair's x before barrier B (HBM hides under S5) ----
        if (!f32 && p == 0) rawload(g0 + 2 + gq);

        __syncthreads();   // (B) pooled vectors ready

        // ---------- S5: heads (2 graphs x 104 outputs) ----------
        if (tid < 208) {
            int gg = (tid >= 104) ? 1 : 0;
            int o  = tid - gg * 104;
            int gh = g0 + p * 2 + gg;
            if (gh < nB) {
                float a = bhf[o];
                const float4* wrow = (const float4*)(whf + o * 128);
                const float4* sp4  = (const float4*)sPool[gg];
#pragma unroll 8
                for (int i = 0; i < 32; ++i) {
                    float4 wv = wrow[i];
                    float4 pv = sp4[i];
                    a += pv.x * wv.x + pv.y * wv.y + pv.z * wv.z + pv.w * wv.w;
                }
                int oo; size_t off;
                if (o < 4)       { oo = o;      off = (size_t)gh * 4 + oo; }
                else if (o < 85) { oo = o - 4;  off = (size_t)nB * 4  + (size_t)gh * 81 + oo; }
                else if (o < 94) { oo = o - 85; off = (size_t)nB * 85 + (size_t)gh * 9  + oo; }
                else             { oo = o - 94; off = (size_t)nB * 94 + (size_t)gh * 10 + oo; }
                if (f32) ((float*)out)[off] = a;
                else     ((unsigned short*)out)[off] = f2b(a);
            }
        }
    }
}

extern "C" void kernel_launch(void* const* d_in, const int* in_sizes, int n_in,
                              void* d_out, int out_size, void* d_ws, size_t ws_size,
                              hipStream_t stream) {
    // setup_inputs order: x, edge_index, batch, W1, b1, W2, b2, Wa, ba, Wc, bc, Wn, bn, Wt, bt
    const void* x  = d_in[0];
    int nB = in_sizes[2] / 81;
    if (nB <= 0) return;

    char* ws = (char*)d_ws;
    hipLaunchKernelGGL(k_repack, dim3(170), dim3(256), 0, stream,
                       x, d_in[3], d_in[4], d_in[5], d_in[6],
                       d_in[7], d_in[8], d_in[9], d_in[10],
                       d_in[11], d_in[12], d_in[13], d_in[14], ws);
    hipLaunchKernelGGL(sudoku_gnn, dim3((nB + 3) / 4), dim3(512), 0, stream,
                       x, (const char*)ws, d_out, nB);
}

// Round 9
// 141.948 us; speedup vs baseline: 1.2971x; 1.2971x over previous
//
#include <hip/hip_runtime.h>
#include <hip/hip_bf16.h>

// Feature-slice GNN with in-register aggregation operands (R6 compute,
// re-sliced for max occupancy): 1024 threads = 16 waves; waves 0-7 = graph A,
// waves 8-15 = graph B; each wave owns a 16-FEATURE slice for all 96 (padded)
// cells. Per-wave state ~55 VGPR -> launch_bounds(1024,8) forces the 64-reg
// cap => 32 waves/CU = 8 waves/SIMD (2x R6's 4). LDS 68.6KB -> 2 blocks/CU,
// exactly the 32-wave budget. D-tile of t = x@W1 packed to bf16 pairs IS the
// B-operand of h = S@t (S A-frags repacked: k-slot q*8+j <-> cell
// (2s+(j>>2))*16+q*4+(j&3)); S1->S2 and S3->S4 are register-only handoffs.
// Only h crosses waves (W2 mixes features): 3 barriers. No lambdas, no
// cross-iteration register arrays (R8's scratch failure mode).
typedef __attribute__((ext_vector_type(8))) short bf16x8;
typedef __attribute__((ext_vector_type(4))) float f32x4;

__device__ __forceinline__ unsigned short f2b(float f) {
    __hip_bfloat16 h = __float2bfloat16(f);
    return __builtin_bit_cast(unsigned short, h);
}
__device__ __forceinline__ float b2f(unsigned short u) {
    unsigned v = ((unsigned)u) << 16;
    return __builtin_bit_cast(float, v);
}
__device__ __forceinline__ float ldf(const void* p, int idx, bool f32) {
    return f32 ? ((const float*)p)[idx] : b2f(((const unsigned short*)p)[idx]);
}
__device__ __forceinline__ unsigned short ldb(const void* p, int idx, bool f32) {
    return f32 ? f2b(((const float*)p)[idx]) : ((const unsigned short*)p)[idx];
}
// XOR chunk swizzle: 128-ushort rows, 8-ushort chunks -> bank-uniform
__device__ __forceinline__ int swz(int row, int col) {
    return row * 128 + (((col >> 3) ^ (row & 7)) << 3) + (col & 7);
}
__device__ __forceinline__ uint2 pk4(f32x4 c) {
    unsigned lo = (unsigned)f2b(c[0]) | ((unsigned)f2b(c[1]) << 16);
    unsigned hi = (unsigned)f2b(c[2]) | ((unsigned)f2b(c[3]) << 16);
    return make_uint2(lo, hi);
}
__device__ __forceinline__ bf16x8 mkB(uint2 a, uint2 b) {
    return __builtin_bit_cast(bf16x8, make_uint4(a.x, a.y, b.x, b.y));
}

// dtype sniff from a uniform 64B of x (fp32 mantissa ushorts -> wild exponents)
__device__ __forceinline__ bool sniff_f32(const void* x) {
    const unsigned* p = (const unsigned*)x;
    int wild = 0;
#pragma unroll
    for (int i = 0; i < 16; ++i) {
        unsigned e = (p[i] >> 7) & 0xFF;
        wild += (e != 0 && (e < 0x68 || e > 0x90)) ? 1 : 0;
    }
    return wild > 8;
}

// ---- ws layout (bytes) ----
#define WS_B1F    16        // 128 f32
#define WS_B2F    528       // 128 f32
#define WS_BHF    1040      // 104 f32
#define WS_W1R    1536      // 128*32 bf16   [f][k]
#define WS_W2R    9728      // 128*128 bf16  [f][k]
#define WS_SR     42496     // 18*64*8 bf16  A-frags [(mt*3+s)*64+lane][j]
#define WS_WH     60928     // 104*128 f32   [o][f]

__global__ void k_repack(const void* __restrict__ x,
                         const void* __restrict__ W1, const void* __restrict__ b1,
                         const void* __restrict__ W2, const void* __restrict__ b2,
                         const void* __restrict__ Wa, const void* __restrict__ ba,
                         const void* __restrict__ Wc, const void* __restrict__ bc,
                         const void* __restrict__ Wn, const void* __restrict__ bn,
                         const void* __restrict__ Wt, const void* __restrict__ bt,
                         char* __restrict__ ws) {
    const bool f32 = sniff_f32(x);
    int idx = blockIdx.x * blockDim.x + threadIdx.x;
    if (idx < 4096) {                         // w1r [f][k]
        int f = idx >> 5, k = idx & 31;
        unsigned short v = (k < 10) ? ldb(W1, k * 128 + f, f32) : (unsigned short)0;
        ((unsigned short*)(ws + WS_W1R))[idx] = v;
        return;
    }
    idx -= 4096;
    if (idx < 16384) {                        // w2r [f][k]
        int f = idx >> 7, k = idx & 127;
        ((unsigned short*)(ws + WS_W2R))[idx] = ldb(W2, k * 128 + f, f32);
        return;
    }
    idx -= 16384;
    if (idx < 9216) {                         // S A-frags, reg-handoff slot layout
        int fi = idx >> 9, rem = idx & 511;
        int lane = rem >> 3, j = rem & 7;
        int mt = fi / 3, s = fi - mt * 3;
        int node = mt * 16 + (lane & 15);                       // m row
        int qa = lane >> 4;                                     // 0..3
        int cell = (2 * s + (j >> 2)) * 16 + qa * 4 + (j & 3);  // k slot -> cell
        bool adj = false;
        if (node < 81 && cell < 81) {
            int ni = node / 9, nj = node % 9;
            int ci = cell / 9, cj = cell % 9;
            adj = (ni == ci) || (nj == cj) ||
                  ((ni / 3 == ci / 3) && (nj / 3 == cj / 3));
        }
        ((unsigned short*)(ws + WS_SR))[idx] = adj ? (unsigned short)0x3F80 : (unsigned short)0;
        return;
    }
    idx -= 9216;
    if (idx < 13312) {                        // head weights (f32) [o][f]
        int o = idx >> 7, f = idx & 127;
        const void* W; int oo, dim;
        if (o < 4)       { W = Wa; oo = o;      dim = 4;  }
        else if (o < 85) { W = Wc; oo = o - 4;  dim = 81; }
        else if (o < 94) { W = Wn; oo = o - 85; dim = 9;  }
        else             { W = Wt; oo = o - 94; dim = 10; }
        ((float*)(ws + WS_WH))[idx] = ldf(W, f * dim + oo, f32);
        return;
    }
    idx -= 13312;
    if (idx < 360) {                          // biases
        float v;
        if (idx < 128)      v = ldf(b1, idx, f32);
        else if (idx < 256) v = ldf(b2, idx - 128, f32);
        else {
            int o = idx - 256;
            if (o < 4)       v = ldf(ba, o, f32);
            else if (o < 85) v = ldf(bc, o - 4, f32);
            else if (o < 94) v = ldf(bn, o - 85, f32);
            else             v = ldf(bt, o - 94, f32);
        }
        if (idx < 128)      ((float*)(ws + WS_B1F))[idx] = v;
        else if (idx < 256) ((float*)(ws + WS_B2F))[idx - 128] = v;
        else                ((float*)(ws + WS_BHF))[idx - 256] = v;
    }
}

__global__ __launch_bounds__(1024, 8) void sudoku_gnn(
    const void* __restrict__ x, const char* __restrict__ ws,
    void* __restrict__ out, int nB)
{
    __shared__ __attribute__((aligned(16))) unsigned short hS[2][12288]; // [96c][128f] swizzled
    __shared__ __attribute__((aligned(16))) unsigned short sS[9216];     // S A-frags
    __shared__ float sPool[2][128];

    const bool f32 = sniff_f32(x);
    const unsigned short* w1r = (const unsigned short*)(ws + WS_W1R);
    const unsigned short* w2r = (const unsigned short*)(ws + WS_W2R);
    const float* b1f = (const float*)(ws + WS_B1F);
    const float* b2f = (const float*)(ws + WS_B2F);
    const float* bhf = (const float*)(ws + WS_BHF);
    const float* whf = (const float*)(ws + WS_WH);

    const int tid  = threadIdx.x;
    const int wave = tid >> 6;            // 0..15
    const int gq   = wave >> 3;           // which graph this wave works on
    const int lane = tid & 63;
    const int ln15 = lane & 15;
    const int q    = lane >> 4;
    const int k0   = q * 8;
    const int FB   = (wave & 7) * 16;     // wave's 16-feature slice base
    const int g0   = blockIdx.x * 2;
    const bool hasB = (g0 + 1 < nB);
    const int g    = (g0 + gq < nB) ? g0 + gq : nB - 1;
    const float inv21 = 1.0f / 21.0f;
    const float inv81 = 1.0f / 81.0f;

    // ---- issue x raw loads first (HBM latency hides under setup) ----
    uint4 xr4[6]; unsigned xr1[6];
    if (!f32) {
        const char* xg = (const char*)x + (size_t)g * 1620;
#pragma unroll
        for (int mt = 0; mt < 6; ++mt) {
            int node = mt * 16 + ln15;
            uint4 r = {0, 0, 0, 0}; unsigned r1v = 0;
            if (node < 81) {
                if (q == 0)      r   = *(const uint4*)(xg + node * 20);
                else if (q == 1) r1v = *(const unsigned*)(xg + node * 20 + 16);
            }
            xr4[mt] = r; xr1[mt] = r1v;
        }
    }

    // ---- stage S A-frags into LDS (consumed after barrier 0) ----
    {
        const uint4* src = (const uint4*)(ws + WS_SR);
        uint4* dst = (uint4*)sS;
        for (int i = tid; i < 1152; i += 1024) dst[i] = src[i];
    }

    // ---- W1 fragment (one per 16-feature slice) ----
    bf16x8 w1f = *(const bf16x8*)&w1r[(FB + ln15) * 32 + k0];

    const f32x4 z4 = {0.f, 0.f, 0.f, 0.f};

    // ---------- S1: t = x @ W1 ; D-tiles -> packed B-frag halves (registers) ----------
    uint2 tpk[6];
#pragma unroll
    for (int mt = 0; mt < 6; ++mt) {
        bf16x8 xv = {0, 0, 0, 0, 0, 0, 0, 0};
        if (!f32) {
            if (q == 0)      xv = __builtin_bit_cast(bf16x8, xr4[mt]);
            else if (q == 1) { xv[0] = (short)(xr1[mt] & 0xFFFF); xv[1] = (short)(xr1[mt] >> 16); }
        } else {
            int node = mt * 16 + ln15;
            if (node < 81) {
                const float* xg = (const float*)x + (size_t)g * 810 + node * 10;
                if (q == 0) {
#pragma unroll
                    for (int j = 0; j < 8; ++j) xv[j] = (short)f2b(xg[j]);
                } else if (q == 1) {
                    xv[0] = (short)f2b(xg[8]);
                    xv[1] = (short)f2b(xg[9]);
                }
            }
        }
        tpk[mt] = pk4(__builtin_amdgcn_mfma_f32_16x16x32_bf16(xv, w1f, z4, 0, 0, 0));
    }
    __syncthreads();   // (0) sS staged

    f32x4 acc[6];

    // ---------- S2: h = S @ t (A from LDS, B from registers) ; relu(+b1) ----------
#pragma unroll
    for (int a = 0; a < 6; ++a) acc[a] = z4;
#pragma unroll
    for (int s = 0; s < 3; ++s) {
        bf16x8 B = mkB(tpk[2 * s], tpk[2 * s + 1]);
#pragma unroll
        for (int mt = 0; mt < 6; ++mt) {
            bf16x8 afr = *(const bf16x8*)&sS[((mt * 3 + s) * 64 + lane) * 8];
            acc[mt] = __builtin_amdgcn_mfma_f32_16x16x32_bf16(afr, B, acc[mt], 0, 0, 0);
        }
    }
    {
        float bias = b1f[FB + ln15];
#pragma unroll
        for (int mt = 0; mt < 6; ++mt)
#pragma unroll
            for (int r = 0; r < 4; ++r) {
                int cell = mt * 16 + q * 4 + r;
                float v = fmaxf(acc[mt][r] * inv21 + bias, 0.0f);
                hS[gq][swz(cell, FB + ln15)] = f2b(v);
            }
    }
    __syncthreads();   // (A) h complete before cross-wave S3 reads

    // ---------- S3: t2 = h @ W2 ; D-tiles -> packed B-frag halves ----------
#pragma unroll
    for (int a = 0; a < 6; ++a) acc[a] = z4;
#pragma unroll
    for (int kc = 0; kc < 4; ++kc) {
        bf16x8 w2f = *(const bf16x8*)&w2r[(FB + ln15) * 128 + kc * 32 + k0];
#pragma unroll
        for (int mt = 0; mt < 6; ++mt) {
            bf16x8 a3 = *(const bf16x8*)&hS[gq][swz(mt * 16 + ln15, kc * 32 + k0)];
            acc[mt] = __builtin_amdgcn_mfma_f32_16x16x32_bf16(a3, w2f, acc[mt], 0, 0, 0);
        }
    }
#pragma unroll
    for (int mt = 0; mt < 6; ++mt)
        tpk[mt] = pk4(acc[mt]);

    // ---------- S4: h2 = S @ t2 (registers) ; relu(+b2) fused mean-pool ----------
#pragma unroll
    for (int a = 0; a < 6; ++a) acc[a] = z4;
#pragma unroll
    for (int s = 0; s < 3; ++s) {
        bf16x8 B = mkB(tpk[2 * s], tpk[2 * s + 1]);
#pragma unroll
        for (int mt = 0; mt < 6; ++mt) {
            bf16x8 afr = *(const bf16x8*)&sS[((mt * 3 + s) * 64 + lane) * 8];
            acc[mt] = __builtin_amdgcn_mfma_f32_16x16x32_bf16(afr, B, acc[mt], 0, 0, 0);
        }
    }
    {
        float bias = b2f[FB + ln15];
        float sum = 0.f;
#pragma unroll
        for (int mt = 0; mt < 6; ++mt)
#pragma unroll
            for (int r = 0; r < 4; ++r) {
                int cell = mt * 16 + q * 4 + r;
                float v = fmaxf(acc[mt][r] * inv21 + bias, 0.0f);
                sum += (cell < 81) ? v : 0.0f;
            }
        sum += __shfl_xor(sum, 16);
        sum += __shfl_xor(sum, 32);
        if (lane < 16) sPool[gq][FB + lane] = sum * inv81;
    }
    __syncthreads();   // (B) pooled vectors ready

    // ---------- S5: heads (2 graphs x 104 outputs) ----------
    if (tid < 208) {
        int gg = (tid >= 104) ? 1 : 0;
        int o  = tid - gg * 104;
        int gh = g0 + gg;
        if (gg == 0 || hasB) {
            float a = bhf[o];
            const float4* wrow = (const float4*)(whf + o * 128);
            const float4* sp4  = (const float4*)sPool[gg];
#pragma unroll 8
            for (int i = 0; i < 32; ++i) {
                float4 wv = wrow[i];
                float4 pv = sp4[i];
                a += pv.x * wv.x + pv.y * wv.y + pv.z * wv.z + pv.w * wv.w;
            }
            int oo; size_t off;
            if (o < 4)       { oo = o;      off = (size_t)gh * 4 + oo; }
            else if (o < 85) { oo = o - 4;  off = (size_t)nB * 4  + (size_t)gh * 81 + oo; }
            else if (o < 94) { oo = o - 85; off = (size_t)nB * 85 + (size_t)gh * 9  + oo; }
            else             { oo = o - 94; off = (size_t)nB * 94 + (size_t)gh * 10 + oo; }
            if (f32) ((float*)out)[off] = a;
            else     ((unsigned short*)out)[off] = f2b(a);
        }
    }
}

extern "C" void kernel_launch(void* const* d_in, const int* in_sizes, int n_in,
                              void* d_out, int out_size, void* d_ws, size_t ws_size,
                              hipStream_t stream) {
    // setup_inputs order: x, edge_index, batch, W1, b1, W2, b2, Wa, ba, Wc, bc, Wn, bn, Wt, bt
    const void* x  = d_in[0];
    int nB = in_sizes[2] / 81;
    if (nB <= 0) return;

    char* ws = (char*)d_ws;
    hipLaunchKernelGGL(k_repack, dim3(170), dim3(256), 0, stream,
                       x, d_in[3], d_in[4], d_in[5], d_in[6],
                       d_in[7], d_in[8], d_in[9], d_in[10],
                       d_in[11], d_in[12], d_in[13], d_in[14], ws);
    hipLaunchKernelGGL(sudoku_gnn, dim3((nB + 1) / 2), dim3(1024), 0, stream,
                       x, (const char*)ws, d_out, nB);
}

// Round 10
// 132.780 us; speedup vs baseline: 1.3866x; 1.0690x over previous
//
#include <hip/hip_runtime.h>
#include <hip/hip_bf16.h>

// Feature-slice GNN with in-register aggregation operands (R6 structure,
// the measured optimum: 512 thr / 8 waves, 2 graphs per block, 4 waves/SIMD).
// This rev, three surgical changes only:
//  1) head weights repacked [i][o] float4-blocked -> S5 global reads coalesced
//     (was [o][f]: 64-line gather per float4 load)
//  2) S5 split 2 threads/output (416 active), halves the 32-deep load chain,
//     combined via shfl_xor(1)
//  3) s_setprio(1/0) around S2/S3/S4 MFMA clusters (independent blocks are
//     phase-skewed -> attn-like regime where setprio measured +4-7%)
// Everything else byte-identical to the 44.8us R6 kernel.
typedef __attribute__((ext_vector_type(8))) short bf16x8;
typedef __attribute__((ext_vector_type(4))) float f32x4;

__device__ __forceinline__ unsigned short f2b(float f) {
    __hip_bfloat16 h = __float2bfloat16(f);
    return __builtin_bit_cast(unsigned short, h);
}
__device__ __forceinline__ float b2f(unsigned short u) {
    unsigned v = ((unsigned)u) << 16;
    return __builtin_bit_cast(float, v);
}
__device__ __forceinline__ float ldf(const void* p, int idx, bool f32) {
    return f32 ? ((const float*)p)[idx] : b2f(((const unsigned short*)p)[idx]);
}
__device__ __forceinline__ unsigned short ldb(const void* p, int idx, bool f32) {
    return f32 ? f2b(((const float*)p)[idx]) : ((const unsigned short*)p)[idx];
}
// XOR chunk swizzle: 128-ushort rows, 8-ushort chunks -> bank-uniform
__device__ __forceinline__ int swz(int row, int col) {
    return row * 128 + (((col >> 3) ^ (row & 7)) << 3) + (col & 7);
}
__device__ __forceinline__ uint2 pk4(f32x4 c) {
    unsigned lo = (unsigned)f2b(c[0]) | ((unsigned)f2b(c[1]) << 16);
    unsigned hi = (unsigned)f2b(c[2]) | ((unsigned)f2b(c[3]) << 16);
    return make_uint2(lo, hi);
}
__device__ __forceinline__ bf16x8 mkB(uint2 a, uint2 b) {
    return __builtin_bit_cast(bf16x8, make_uint4(a.x, a.y, b.x, b.y));
}

// dtype sniff from a uniform 64B of x (fp32 mantissa ushorts -> wild exponents)
__device__ __forceinline__ bool sniff_f32(const void* x) {
    const unsigned* p = (const unsigned*)x;
    int wild = 0;
#pragma unroll
    for (int i = 0; i < 16; ++i) {
        unsigned e = (p[i] >> 7) & 0xFF;
        wild += (e != 0 && (e < 0x68 || e > 0x90)) ? 1 : 0;
    }
    return wild > 8;
}

// ---- ws layout (bytes) ----
#define WS_B1F    16        // 128 f32
#define WS_B2F    528       // 128 f32
#define WS_BHF    1040      // 104 f32
#define WS_W1R    1536      // 128*32 bf16   [f][k]
#define WS_W2R    9728      // 128*128 bf16  [f][k]
#define WS_SR     42496     // 18*64*8 bf16  A-frags [(mt*3+s)*64+lane][j]
#define WS_WH     60928     // 104*128 f32, [i][o][c] blocked: wh4[i*104+o] = W[4i..4i+3][o]

__global__ void k_repack(const void* __restrict__ x,
                         const void* __restrict__ W1, const void* __restrict__ b1,
                         const void* __restrict__ W2, const void* __restrict__ b2,
                         const void* __restrict__ Wa, const void* __restrict__ ba,
                         const void* __restrict__ Wc, const void* __restrict__ bc,
                         const void* __restrict__ Wn, const void* __restrict__ bn,
                         const void* __restrict__ Wt, const void* __restrict__ bt,
                         char* __restrict__ ws) {
    const bool f32 = sniff_f32(x);
    int idx = blockIdx.x * blockDim.x + threadIdx.x;
    if (idx < 4096) {                         // w1r [f][k]
        int f = idx >> 5, k = idx & 31;
        unsigned short v = (k < 10) ? ldb(W1, k * 128 + f, f32) : (unsigned short)0;
        ((unsigned short*)(ws + WS_W1R))[idx] = v;
        return;
    }
    idx -= 4096;
    if (idx < 16384) {                        // w2r [f][k]
        int f = idx >> 7, k = idx & 127;
        ((unsigned short*)(ws + WS_W2R))[idx] = ldb(W2, k * 128 + f, f32);
        return;
    }
    idx -= 16384;
    if (idx < 9216) {                         // S A-frags, reg-handoff slot layout
        int fi = idx >> 9, rem = idx & 511;
        int lane = rem >> 3, j = rem & 7;
        int mt = fi / 3, s = fi - mt * 3;
        int node = mt * 16 + (lane & 15);                       // m row
        int qa = lane >> 4;                                     // 0..3
        int cell = (2 * s + (j >> 2)) * 16 + qa * 4 + (j & 3);  // k slot -> cell
        bool adj = false;
        if (node < 81 && cell < 81) {
            int ni = node / 9, nj = node % 9;
            int ci = cell / 9, cj = cell % 9;
            adj = (ni == ci) || (nj == cj) ||
                  ((ni / 3 == ci / 3) && (nj / 3 == cj / 3));
        }
        ((unsigned short*)(ws + WS_SR))[idx] = adj ? (unsigned short)0x3F80 : (unsigned short)0;
        return;
    }
    idx -= 9216;
    if (idx < 13312) {                        // head weights (f32) [i][o][c] blocked
        int i = idx / 416;                    // feature block 0..31
        int rem = idx - i * 416;
        int o = rem >> 2;                     // output 0..103
        int c = rem & 3;
        int f = i * 4 + c;
        const void* W; int oo, dim;
        if (o < 4)       { W = Wa; oo = o;      dim = 4;  }
        else if (o < 85) { W = Wc; oo = o - 4;  dim = 81; }
        else if (o < 94) { W = Wn; oo = o - 85; dim = 9;  }
        else             { W = Wt; oo = o - 94; dim = 10; }
        ((float*)(ws + WS_WH))[idx] = ldf(W, f * dim + oo, f32);
        return;
    }
    idx -= 13312;
    if (idx < 360) {                          // biases
        float v;
        if (idx < 128)      v = ldf(b1, idx, f32);
        else if (idx < 256) v = ldf(b2, idx - 128, f32);
        else {
            int o = idx - 256;
            if (o < 4)       v = ldf(ba, o, f32);
            else if (o < 85) v = ldf(bc, o - 4, f32);
            else if (o < 94) v = ldf(bn, o - 85, f32);
            else             v = ldf(bt, o - 94, f32);
        }
        if (idx < 128)      ((float*)(ws + WS_B1F))[idx] = v;
        else if (idx < 256) ((float*)(ws + WS_B2F))[idx - 128] = v;
        else                ((float*)(ws + WS_BHF))[idx - 256] = v;
    }
}

__global__ __launch_bounds__(512, 4) void sudoku_gnn(
    const void* __restrict__ x, const char* __restrict__ ws,
    void* __restrict__ out, int nB)
{
    __shared__ __attribute__((aligned(16))) unsigned short hS[2][12288]; // [96c][128f] swizzled
    __shared__ __attribute__((aligned(16))) unsigned short sS[9216];     // S A-frags
    __shared__ float sPool[2][128];

    const bool f32 = sniff_f32(x);
    const unsigned short* w1r = (const unsigned short*)(ws + WS_W1R);
    const unsigned short* w2r = (const unsigned short*)(ws + WS_W2R);
    const float* b1f = (const float*)(ws + WS_B1F);
    const float* b2f = (const float*)(ws + WS_B2F);
    const float* bhf = (const float*)(ws + WS_BHF);
    const float* whf = (const float*)(ws + WS_WH);

    const int tid  = threadIdx.x;
    const int wave = tid >> 6;
    const int gq   = wave >> 2;           // which graph this wave works on
    const int lane = tid & 63;
    const int ln15 = lane & 15;
    const int q    = lane >> 4;
    const int k0   = q * 8;
    const int FB   = (wave & 3) * 32;     // wave's feature-slice base
    const int g0   = blockIdx.x * 2;
    const bool hasB = (g0 + 1 < nB);
    const int g    = (g0 + gq < nB) ? g0 + gq : nB - 1;
    const float inv21 = 1.0f / 21.0f;
    const float inv81 = 1.0f / 81.0f;

    // ---- issue x raw loads first (HBM latency hides under setup) ----
    uint4 xr4[6]; unsigned xr1[6];
    if (!f32) {
        const char* xg = (const char*)x + (size_t)g * 1620;
#pragma unroll
        for (int mt = 0; mt < 6; ++mt) {
            int node = mt * 16 + ln15;
            uint4 r = {0, 0, 0, 0}; unsigned r1v = 0;
            if (node < 81) {
                if (q == 0)      r   = *(const uint4*)(xg + node * 20);
                else if (q == 1) r1v = *(const unsigned*)(xg + node * 20 + 16);
            }
            xr4[mt] = r; xr1[mt] = r1v;
        }
    }

    // ---- stage S A-frags into LDS (consumed after barrier 0) ----
    {
        const uint4* src = (const uint4*)(ws + WS_SR);
        uint4* dst = (uint4*)sS;
        for (int i = tid; i < 1152; i += 512) dst[i] = src[i];
    }

    // ---- W1 fragments ----
    bf16x8 w1f[2];
#pragma unroll
    for (int fmt = 0; fmt < 2; ++fmt)
        w1f[fmt] = *(const bf16x8*)&w1r[(FB + fmt * 16 + ln15) * 32 + k0];

    const f32x4 z4 = {0.f, 0.f, 0.f, 0.f};

    // ---------- S1: t = x @ W1 ; D-tiles -> packed B-frag halves (registers) ----------
    uint2 tpk[6][2];
#pragma unroll
    for (int mt = 0; mt < 6; ++mt) {
        bf16x8 xv = {0, 0, 0, 0, 0, 0, 0, 0};
        if (!f32) {
            if (q == 0)      xv = __builtin_bit_cast(bf16x8, xr4[mt]);
            else if (q == 1) { xv[0] = (short)(xr1[mt] & 0xFFFF); xv[1] = (short)(xr1[mt] >> 16); }
        } else {
            int node = mt * 16 + ln15;
            if (node < 81) {
                const float* xg = (const float*)x + (size_t)g * 810 + node * 10;
                if (q == 0) {
#pragma unroll
                    for (int j = 0; j < 8; ++j) xv[j] = (short)f2b(xg[j]);
                } else if (q == 1) {
                    xv[0] = (short)f2b(xg[8]);
                    xv[1] = (short)f2b(xg[9]);
                }
            }
        }
#pragma unroll
        for (int fmt = 0; fmt < 2; ++fmt)
            tpk[mt][fmt] = pk4(__builtin_amdgcn_mfma_f32_16x16x32_bf16(xv, w1f[fmt], z4, 0, 0, 0));
    }
    __syncthreads();   // (0) sS staged

    f32x4 acc[6][2];

    // ---------- S2: h = S @ t (B from registers) ; relu(+b1) ----------
#pragma unroll
    for (int a = 0; a < 6; ++a)
#pragma unroll
        for (int c = 0; c < 2; ++c) acc[a][c] = z4;
    __builtin_amdgcn_s_setprio(1);
#pragma unroll
    for (int s = 0; s < 3; ++s) {
        bf16x8 B[2];
#pragma unroll
        for (int fmt = 0; fmt < 2; ++fmt)
            B[fmt] = mkB(tpk[2 * s][fmt], tpk[2 * s + 1][fmt]);
#pragma unroll
        for (int mt = 0; mt < 6; ++mt) {
            bf16x8 afr = *(const bf16x8*)&sS[((mt * 3 + s) * 64 + lane) * 8];
#pragma unroll
            for (int fmt = 0; fmt < 2; ++fmt)
                acc[mt][fmt] = __builtin_amdgcn_mfma_f32_16x16x32_bf16(afr, B[fmt], acc[mt][fmt], 0, 0, 0);
        }
    }
    __builtin_amdgcn_s_setprio(0);
#pragma unroll
    for (int fmt = 0; fmt < 2; ++fmt) {
        float bias = b1f[FB + fmt * 16 + ln15];
#pragma unroll
        for (int mt = 0; mt < 6; ++mt)
#pragma unroll
            for (int r = 0; r < 4; ++r) {
                int cell = mt * 16 + q * 4 + r;
                float v = fmaxf(acc[mt][fmt][r] * inv21 + bias, 0.0f);
                hS[gq][swz(cell, FB + fmt * 16 + ln15)] = f2b(v);
            }
    }
    __syncthreads();   // (A) h complete before cross-wave S3 reads

    // ---------- S3: t2 = h @ W2 ; D-tiles -> packed B-frag halves ----------
#pragma unroll
    for (int a = 0; a < 6; ++a)
#pragma unroll
        for (int c = 0; c < 2; ++c) acc[a][c] = z4;
    __builtin_amdgcn_s_setprio(1);
#pragma unroll
    for (int kc = 0; kc < 4; ++kc) {
        bf16x8 w2f[2];
#pragma unroll
        for (int fmt = 0; fmt < 2; ++fmt)
            w2f[fmt] = *(const bf16x8*)&w2r[(FB + fmt * 16 + ln15) * 128 + kc * 32 + k0];
#pragma unroll
        for (int mt = 0; mt < 6; ++mt) {
            bf16x8 a3 = *(const bf16x8*)&hS[gq][swz(mt * 16 + ln15, kc * 32 + k0)];
#pragma unroll
            for (int fmt = 0; fmt < 2; ++fmt)
                acc[mt][fmt] = __builtin_amdgcn_mfma_f32_16x16x32_bf16(a3, w2f[fmt], acc[mt][fmt], 0, 0, 0);
        }
    }
    __builtin_amdgcn_s_setprio(0);
#pragma unroll
    for (int mt = 0; mt < 6; ++mt)
#pragma unroll
        for (int fmt = 0; fmt < 2; ++fmt)
            tpk[mt][fmt] = pk4(acc[mt][fmt]);

    // ---------- S4: h2 = S @ t2 (registers) ; relu(+b2) fused mean-pool ----------
#pragma unroll
    for (int a = 0; a < 6; ++a)
#pragma unroll
        for (int c = 0; c < 2; ++c) acc[a][c] = z4;
    __builtin_amdgcn_s_setprio(1);
#pragma unroll
    for (int s = 0; s < 3; ++s) {
        bf16x8 B[2];
#pragma unroll
        for (int fmt = 0; fmt < 2; ++fmt)
            B[fmt] = mkB(tpk[2 * s][fmt], tpk[2 * s + 1][fmt]);
#pragma unroll
        for (int mt = 0; mt < 6; ++mt) {
            bf16x8 afr = *(const bf16x8*)&sS[((mt * 3 + s) * 64 + lane) * 8];
#pragma unroll
            for (int fmt = 0; fmt < 2; ++fmt)
                acc[mt][fmt] = __builtin_amdgcn_mfma_f32_16x16x32_bf16(afr, B[fmt], acc[mt][fmt], 0, 0, 0);
        }
    }
    __builtin_amdgcn_s_setprio(0);
#pragma unroll
    for (int fmt = 0; fmt < 2; ++fmt) {
        float bias = b2f[FB + fmt * 16 + ln15];
        float sum = 0.f;
#pragma unroll
        for (int mt = 0; mt < 6; ++mt)
#pragma unroll
            for (int r = 0; r < 4; ++r) {
                int cell = mt * 16 + q * 4 + r;
                float v = fmaxf(acc[mt][fmt][r] * inv21 + bias, 0.0f);
                sum += (cell < 81) ? v : 0.0f;
            }
        sum += __shfl_xor(sum, 16);
        sum += __shfl_xor(sum, 32);
        if (lane < 16) sPool[gq][FB + fmt * 16 + lane] = sum * inv81;
    }
    __syncthreads();   // (B) pooled vectors ready

    // ---------- S5: heads, 2 threads per output (416 active), coalesced wh4 ----------
    if (tid < 416) {
        int pr = tid >> 1, hf = tid & 1;
        int gg = (pr >= 104) ? 1 : 0;
        int o  = pr - gg * 104;
        int gh = g0 + gg;
        float a = 0.0f;
        if (gg == 0 || hasB) {
            a = hf ? 0.0f : bhf[o];
            const float4* wh4 = (const float4*)whf;
            const float4* sp4 = (const float4*)sPool[gg];
#pragma unroll
            for (int ii = 0; ii < 16; ++ii) {
                int i = hf * 16 + ii;
                float4 wv = wh4[i * 104 + o];
                float4 pv = sp4[i];
                a += pv.x * wv.x + pv.y * wv.y + pv.z * wv.z + pv.w * wv.w;
            }
        }
        a += __shfl_xor(a, 1);
        if (hf == 0 && (gg == 0 || hasB)) {
            int oo; size_t off;
            if (o < 4)       { oo = o;      off = (size_t)gh * 4 + oo; }
            else if (o < 85) { oo = o - 4;  off = (size_t)nB * 4  + (size_t)gh * 81 + oo; }
            else if (o < 94) { oo = o - 85; off = (size_t)nB * 85 + (size_t)gh * 9  + oo; }
            else             { oo = o - 94; off = (size_t)nB * 94 + (size_t)gh * 10 + oo; }
            if (f32) ((float*)out)[off] = a;
            else     ((unsigned short*)out)[off] = f2b(a);
        }
    }
}

extern "C" void kernel_launch(void* const* d_in, const int* in_sizes, int n_in,
                              void* d_out, int out_size, void* d_ws, size_t ws_size,
                              hipStream_t stream) {
    // setup_inputs order: x, edge_index, batch, W1, b1, W2, b2, Wa, ba, Wc, bc, Wn, bn, Wt, bt
    const void* x  = d_in[0];
    int nB = in_sizes[2] / 81;
    if (nB <= 0) return;

    char* ws = (char*)d_ws;
    hipLaunchKernelGGL(k_repack, dim3(170), dim3(256), 0, stream,
                       x, d_in[3], d_in[4], d_in[5], d_in[6],
                       d_in[7], d_in[8], d_in[9], d_in[10],
                       d_in[11], d_in[12], d_in[13], d_in[14], ws);
    hipLaunchKernelGGL(sudoku_gnn, dim3((nB + 1) / 2), dim3(512), 0, stream,
                       x, (const char*)ws, d_out, nB);
}